// Round 2
// baseline (597.900 us; speedup 1.0000x reference)
//
#include <hip/hip_runtime.h>

// h[t] = a[t]*h[t-1] + b[t] along axis S of (B,S,D,N) = (2,2048,1024,16), fp32.
// 32768 independent chains (one per (b,d,n)), scan stride = D*N elements.
// Distance-2 software pipeline: while computing batch k, batch k+1 is loaded
// and batch k+2 is in flight -> keeps the per-wave vmcnt window (~63 ops) full.

constexpr int S_LEN         = 2048;
constexpr int DN            = 1024 * 16;          // 16384 chains per batch
constexpr long BATCH_STRIDE = (long)S_LEN * DN;   // elements per batch
constexpr int NCHAIN        = 2 * DN;             // 32768 total chains
constexpr int U             = 16;                 // steps per batch
constexpr int NIT           = S_LEN / U;          // 128 batches

__device__ __forceinline__ void load_batch(const float* __restrict__ ap,
                                           const float* __restrict__ bp,
                                           size_t off, float* av, float* bv) {
    #pragma unroll
    for (int u = 0; u < U; ++u) {
        av[u] = ap[off + (size_t)u * DN];
        bv[u] = bp[off + (size_t)u * DN];
    }
}

__device__ __forceinline__ float compute_batch(float h, const float* av, const float* bv,
                                               float* __restrict__ op, size_t off) {
    #pragma unroll
    for (int u = 0; u < U; ++u) {
        h = fmaf(av[u], h, bv[u]);
        __builtin_nontemporal_store(h, &op[off + (size_t)u * DN]);
    }
    return h;
}

__global__ __launch_bounds__(64) void scan_chain_kernel(
    const float* __restrict__ a,
    const float* __restrict__ b,
    float* __restrict__ out)
{
    const int m  = blockIdx.x * 64 + threadIdx.x;   // chain id, 0..32767
    const int bi = m >> 14;                          // m / DN
    const int dn = m & (DN - 1);                     // m % DN
    const size_t base = (size_t)bi * BATCH_STRIDE + dn;

    const float* __restrict__ ap = a + base;
    const float* __restrict__ bp = b + base;
    float* __restrict__ op = out + base;

    const size_t step = (size_t)U * DN;

    float a0[U], b0[U], a1[U], b1[U];
    load_batch(ap, bp, 0,    a0, b0);   // batch 0
    load_batch(ap, bp, step, a1, b1);   // batch 1

    float h = 0.0f;
    size_t offC = 0;
    // Main loop: computes batches k (buf0) and k+1 (buf1), prefetches k+2, k+3.
    // Last k in loop = NIT-4 -> prefetches batches NIT-2, NIT-1.
    for (int k = 0; k < NIT - 2; k += 2) {
        h = compute_batch(h, a0, b0, op, offC);
        load_batch(ap, bp, offC + 2 * step, a0, b0);
        h = compute_batch(h, a1, b1, op, offC + step);
        load_batch(ap, bp, offC + 3 * step, a1, b1);
        offC += 2 * step;
    }
    // Epilogue: batches NIT-2, NIT-1 (already loaded).
    h = compute_batch(h, a0, b0, op, offC);
    h = compute_batch(h, a1, b1, op, offC + step);
}

extern "C" void kernel_launch(void* const* d_in, const int* in_sizes, int n_in,
                              void* d_out, int out_size, void* d_ws, size_t ws_size,
                              hipStream_t stream) {
    const float* a = (const float*)d_in[0];
    const float* b = (const float*)d_in[1];
    float* out = (float*)d_out;

    dim3 grid(NCHAIN / 64);   // 512 blocks
    dim3 block(64);           // 1 wave each -> 2 waves/CU across 256 CUs
    scan_chain_kernel<<<grid, block, 0, stream>>>(a, b, out);
}